// Round 6
// baseline (289.159 us; speedup 1.0000x reference)
//
#include <hip/hip_runtime.h>

// Problem constants
#define BATCH   4
#define SEQ     2048
#define DMODEL  1024
#define NHEADS  16
#define HDIM    64
// SCALE * log2(e) folded into Q at the GEMM epilogue: exp(s*0.125) = exp2(s*QSC)
#define QSC     0.18033688f

typedef short s16x8 __attribute__((ext_vector_type(8)));
typedef float f32x4 __attribute__((ext_vector_type(4)));
typedef const __attribute__((address_space(1))) unsigned int* gas_t;
typedef __attribute__((address_space(3))) unsigned int* las_t;

__device__ inline unsigned short f2bf(float f) {
    unsigned int u = __float_as_uint(f);
    u += 0x7FFF + ((u >> 16) & 1);   // RNE
    return (unsigned short)(u >> 16);
}

__device__ __forceinline__ float exp2_fast(float x) {
#if __has_builtin(__builtin_amdgcn_exp2f)
    return __builtin_amdgcn_exp2f(x);
#else
    return exp2f(x);
#endif
}

__device__ __forceinline__ float rcp_fast(float x) {
#if __has_builtin(__builtin_amdgcn_rcpf)
    return __builtin_amdgcn_rcpf(x);
#else
    return 1.0f / x;
#endif
}

// pack two floats to bf16x2 (round-half-up), lo in low 16 bits
__device__ __forceinline__ unsigned int pack_bf16x2(float lo, float hi) {
    unsigned int a = __float_as_uint(lo) + 0x8000u;
    unsigned int b = __float_as_uint(hi) + 0x8000u;
#if __has_builtin(__builtin_amdgcn_perm)
    return __builtin_amdgcn_perm(b, a, 0x07060302u);
#else
    return (a >> 16) | (b & 0xFFFF0000u);
#endif
}

// ---------------- QKV projection GEMM ----------------
// C[m,o] = sum_k X[m,k] * W[o,k]  (M=8192, N=3072, K=1024), fp32 in, bf16 out.
// fp32->bf16 convert fused into LDS staging. Stride-40 rows (write conflicts
// at the b128 floor). 2-step prefetch: gload(k+64) issued one full compute
// step before its swrite.
#define GSTR 40

__global__ __launch_bounds__(256, 2) void qkv_gemm(
    const float* __restrict__ X,
    const float* __restrict__ W,
    unsigned short* __restrict__ Qo,
    unsigned short* __restrict__ Ko,
    unsigned short* __restrict__ Vt)
{
    __shared__ __align__(16) unsigned short As[2][128 * GSTR];
    __shared__ __align__(16) unsigned short Bs[2][128 * GSTR];

    const int t    = threadIdx.x;
    const int m0   = blockIdx.y * 128;
    const int n0   = blockIdx.x * 128;
    const int wid  = t >> 6;
    const int lane = t & 63;
    const int l15  = lane & 15;
    const int quad = lane >> 4;
    const int wm   = (wid >> 1) * 64;
    const int wn   = (wid & 1) * 64;

    // staging: 2 threads per row, 16 elems each
    const int srow = t >> 1;
    const int koff = (t & 1) * 16;

    const float* gA = &X[(size_t)(m0 + srow) * 1024 + koff];
    const float* gB = &W[(size_t)(n0 + srow) * 1024 + koff];

    f32x4 acc[4][4] = {};
    float4 sa0[4], sb0[4], sa1[4], sb1[4];

    auto gloadf = [&](int k0, float4 (&a)[4], float4 (&b)[4]) {
        const float4* pa = (const float4*)(gA + k0);
        a[0] = pa[0]; a[1] = pa[1]; a[2] = pa[2]; a[3] = pa[3];
        const float4* pb = (const float4*)(gB + k0);
        b[0] = pb[0]; b[1] = pb[1]; b[2] = pb[2]; b[3] = pb[3];
    };
    auto swrite = [&](int buf, float4 (&a)[4], float4 (&b)[4]) {
        uint4 u;
        u.x = pack_bf16x2(a[0].x, a[0].y); u.y = pack_bf16x2(a[0].z, a[0].w);
        u.z = pack_bf16x2(a[1].x, a[1].y); u.w = pack_bf16x2(a[1].z, a[1].w);
        *(uint4*)&As[buf][srow * GSTR + koff] = u;
        u.x = pack_bf16x2(a[2].x, a[2].y); u.y = pack_bf16x2(a[2].z, a[2].w);
        u.z = pack_bf16x2(a[3].x, a[3].y); u.w = pack_bf16x2(a[3].z, a[3].w);
        *(uint4*)&As[buf][srow * GSTR + koff + 8] = u;
        u.x = pack_bf16x2(b[0].x, b[0].y); u.y = pack_bf16x2(b[0].z, b[0].w);
        u.z = pack_bf16x2(b[1].x, b[1].y); u.w = pack_bf16x2(b[1].z, b[1].w);
        *(uint4*)&Bs[buf][srow * GSTR + koff] = u;
        u.x = pack_bf16x2(b[2].x, b[2].y); u.y = pack_bf16x2(b[2].z, b[2].w);
        u.z = pack_bf16x2(b[3].x, b[3].y); u.w = pack_bf16x2(b[3].z, b[3].w);
        *(uint4*)&Bs[buf][srow * GSTR + koff + 8] = u;
    };
    auto cstep = [&](int buf) {
        s16x8 af[4], bf[4];
        #pragma unroll
        for (int mt = 0; mt < 4; mt++)
            af[mt] = *(const s16x8*)&As[buf][(wm + mt * 16 + l15) * GSTR + quad * 8];
        #pragma unroll
        for (int nt = 0; nt < 4; nt++)
            bf[nt] = *(const s16x8*)&Bs[buf][(wn + nt * 16 + l15) * GSTR + quad * 8];
        #pragma unroll
        for (int mt = 0; mt < 4; mt++)
            #pragma unroll
            for (int nt = 0; nt < 4; nt++)
                acc[mt][nt] = __builtin_amdgcn_mfma_f32_16x16x32_bf16(
                    af[mt], bf[nt], acc[mt][nt], 0, 0, 0);
    };

    // prologue: buf0 <- k0, regs1 <- k32
    gloadf(0, sa0, sb0);
    swrite(0, sa0, sb0);
    gloadf(32, sa1, sb1);
    __syncthreads();

    #pragma unroll 1
    for (int kk = 0; kk < 1024; kk += 64) {
        if (kk + 64 < 1024) gloadf(kk + 64, sa0, sb0);
        cstep(0);
        swrite(1, sa1, sb1);
        __syncthreads();
        if (kk + 96 < 1024) gloadf(kk + 96, sa1, sb1);
        cstep(1);
        if (kk + 64 < 1024) swrite(0, sa0, sb0);
        __syncthreads();
    }

    // epilogue: C/D layout col=l15, row=quad*4+r
    #pragma unroll
    for (int mt = 0; mt < 4; mt++) {
        const int mbase = m0 + wm + mt * 16 + quad * 4;
        #pragma unroll
        for (int nt = 0; nt < 4; nt++) {
            const int o  = n0 + wn + nt * 16 + l15;
            const int p  = o >> 10;
            const int oo = o & 1023;
            const int h  = oo >> 6;
            const int d  = oo & 63;
            #pragma unroll
            for (int r = 0; r < 4; r++) {
                const int mm = mbase + r;
                const int b  = mm >> 11;
                const int n  = mm & 2047;
                float v = acc[mt][nt][r];
                if (p == 0)
                    Qo[((size_t)(b * 16 + h) * 2048 + n) * 64 + d] = f2bf(v * QSC);
                else if (p == 1)
                    Ko[((size_t)(b * 16 + h) * 2048 + n) * 64 + d] = f2bf(v);
                else
                    Vt[((size_t)(b * 16 + h) * 64 + d) * 2048 + n] = f2bf(v);
            }
        }
    }
}

// ---------------- fused attention ----------------
// 4 waves x 64 Q-rows (256 rows/block), grid (8,64) = 2 blocks/CU.
// K/V double-buffered in LDS via global_load_lds (async DMA), ONE barrier per
// step: stage(t+1,buf^1) -> compute(buf) -> barrier (drain covered by compute).
// XOR swizzle (chunk ^= row&7) for conflict-free b128 reads under lane-linear
// DMA. LDS map (ushort): K0@0,V0@4096,K1@8192,V1@12288, P@16384+w*4608.
#define PSTRIDE 72
#define PBASE   16384

__global__ __launch_bounds__(256, 2) void attn(
    const unsigned short* __restrict__ Q,
    const unsigned short* __restrict__ K,
    const unsigned short* __restrict__ Vt,
    float* __restrict__ out)
{
    __shared__ __align__(16) unsigned short LDS[PBASE + 4 * 64 * PSTRIDE];

    const int t    = threadIdx.x;
    const int w    = t >> 6;
    const int lane = t & 63;
    const int l15  = lane & 15;
    const int quad = lane >> 4;
    const int head = blockIdx.y;            // b*16 + h
    const int b    = head >> 4;
    const int h    = head & 15;
    const int q0   = blockIdx.x * 256 + w * 64;

    const unsigned short* Qh = Q  + (size_t)head * 2048 * 64;
    const unsigned short* Kh = K  + (size_t)head * 2048 * 64;
    const unsigned short* Vh = Vt + (size_t)head * 64 * 2048;

    // staging: phys chunk i = rd*256 + t holds logical (row=i>>3, col=(i&7)^(row&7))
    const int r0 = t >> 3;
    const int c0 = (t & 7) ^ (r0 & 7);
    const unsigned short* srcK = Kh + r0 * 64 + c0 * 8;
    const unsigned short* srcV = Vh + r0 * 2048 + c0 * 8;

    auto stage = [&](int kt, int bufE) {
        #pragma unroll
        for (int rd = 0; rd < 2; rd++) {
            __builtin_amdgcn_global_load_lds(
                (gas_t)(const void*)(srcK + kt * 4096 + rd * 2048),
                (las_t)(void*)&LDS[bufE + rd * 2048 + w * 512], 16, 0, 0);
            __builtin_amdgcn_global_load_lds(
                (gas_t)(const void*)(srcV + kt * 64 + rd * 65536),
                (las_t)(void*)&LDS[bufE + 4096 + rd * 2048 + w * 512], 16, 0, 0);
        }
    };

    // Q fragments (pre-scaled by QSC in gemm), B-operand role; 64 rows
    s16x8 qb[4][2];
    #pragma unroll
    for (int mt = 0; mt < 4; mt++)
        #pragma unroll
        for (int kc = 0; kc < 2; kc++)
            qb[mt][kc] = *(const s16x8*)&Qh[(size_t)(q0 + mt * 16 + l15) * 64 + kc * 32 + quad * 8];

    f32x4 y[4][4] = {};
    float lsum[4] = {0.f, 0.f, 0.f, 0.f};
    unsigned short* P = &LDS[PBASE + w * (64 * PSTRIDE)];

    // swizzled in-tile column offsets (elems) for kc=0/1
    const int x7   = l15 & 7;
    const int csw0 = (quad ^ x7) * 8;
    const int csw1 = ((4 + quad) ^ x7) * 8;

    stage(0, 0);
    __syncthreads();

    #pragma unroll 1
    for (int kt = 0; kt < 32; kt++) {
        const int bufE = (kt & 1) * 8192;
        if (kt + 1 < 32) stage(kt + 1, 8192 - bufE);   // DMA overlaps compute

        // K fragments + QK MFMAs
        s16x8 kb[4][2];
        #pragma unroll
        for (int nt = 0; nt < 4; nt++) {
            const int rowb = bufE + (nt * 16 + l15) * 64;
            kb[nt][0] = *(const s16x8*)&LDS[rowb + csw0];
            kb[nt][1] = *(const s16x8*)&LDS[rowb + csw1];
        }
        f32x4 st[4][4] = {};      // st[nt][mt]
        #pragma unroll
        for (int kc = 0; kc < 2; kc++)
            #pragma unroll
            for (int nt = 0; nt < 4; nt++)
                #pragma unroll
                for (int mt = 0; mt < 4; mt++)
                    st[nt][mt] = __builtin_amdgcn_mfma_f32_16x16x32_bf16(
                        kb[nt][kc], qb[mt][kc], st[nt][mt], 0, 0, 0);

        // V fragments
        s16x8 vb[4][2];
        #pragma unroll
        for (int dt = 0; dt < 4; dt++) {
            const int rowb = bufE + 4096 + (dt * 16 + l15) * 64;
            vb[dt][0] = *(const s16x8*)&LDS[rowb + csw0];
            vb[dt][1] = *(const s16x8*)&LDS[rowb + csw1];
        }

        // exp2 + pack + ds_write_b64 into per-wave P region
        #pragma unroll
        for (int mt = 0; mt < 4; mt++)
            #pragma unroll
            for (int nt = 0; nt < 4; nt++) {
                float p0 = exp2_fast(st[nt][mt][0]);
                float p1 = exp2_fast(st[nt][mt][1]);
                float p2 = exp2_fast(st[nt][mt][2]);
                float p3 = exp2_fast(st[nt][mt][3]);
                lsum[mt] += (p0 + p1) + (p2 + p3);
                uint2 u;
                u.x = pack_bf16x2(p0, p1);
                u.y = pack_bf16x2(p2, p3);
                *(uint2*)&P[(mt * 16 + l15) * PSTRIDE + nt * 16 + quad * 4] = u;
            }

        // Y += P V
        #pragma unroll
        for (int kc = 0; kc < 2; kc++) {
            s16x8 pa[4];
            #pragma unroll
            for (int mt = 0; mt < 4; mt++)
                pa[mt] = *(const s16x8*)&P[(mt * 16 + l15) * PSTRIDE + kc * 32 + quad * 8];
            #pragma unroll
            for (int mt = 0; mt < 4; mt++)
                #pragma unroll
                for (int dt = 0; dt < 4; dt++)
                    y[mt][dt] = __builtin_amdgcn_mfma_f32_16x16x32_bf16(
                        pa[mt], vb[dt][kc], y[mt][dt], 0, 0, 0);
        }

        __syncthreads();   // buf^1 DMA drained; all reads of buf done
    }

    // reduce lsum across quads (lanes sharing l15 hold disjoint n-subsets)
    #pragma unroll
    for (int mt = 0; mt < 4; mt++) {
        float v = lsum[mt];
        v += __shfl_xor(v, 16);
        v += __shfl_xor(v, 32);
        lsum[mt] = v;
    }

    float rinv[4][4];
    #pragma unroll
    for (int mt = 0; mt < 4; mt++)
        #pragma unroll
        for (int r = 0; r < 4; r++)
            rinv[mt][r] = rcp_fast(__shfl(lsum[mt], quad * 4 + r));

    // out[b, n, h*64+d] fp32; C-layout: col=l15 -> d, row=quad*4+r -> m
    #pragma unroll
    for (int mt = 0; mt < 4; mt++)
        #pragma unroll
        for (int dt = 0; dt < 4; dt++)
            #pragma unroll
            for (int r = 0; r < 4; r++) {
                const int n = q0 + mt * 16 + quad * 4 + r;
                const int d = dt * 16 + l15;
                out[((size_t)(b * 2048 + n)) * 1024 + h * 64 + d] =
                    y[mt][dt][r] * rinv[mt][r];
            }
}

// ---------------- launch ----------------
extern "C" void kernel_launch(void* const* d_in, const int* in_sizes, int n_in,
                              void* d_out, int out_size, void* d_ws, size_t ws_size,
                              hipStream_t stream) {
    const float* X = (const float*)d_in[0];   // [4,2048,1024]
    const float* W = (const float*)d_in[1];   // [3072,1024]
    float* out = (float*)d_out;

    char* ws = (char*)d_ws;
    unsigned short* Qb = (unsigned short*)(ws);                 // 16.8 MB
    unsigned short* Kb = (unsigned short*)(ws + 16777216);      // 16.8 MB
    unsigned short* Vt = (unsigned short*)(ws + 33554432);      // 16.8 MB (ends 50.3 MB)

    qkv_gemm<<<dim3(24, 64), dim3(256), 0, stream>>>(X, W, Qb, Kb, Vt);
    attn<<<dim3(8, 64), dim3(256), 0, stream>>>(Qb, Kb, Vt, out);
}